// Round 2
// 8196.339 us; speedup vs baseline: 1.9531x; 1.9531x over previous
//
#include <hip/hip_runtime.h>
#include <math.h>

// Literal-dataflow kernel, DAG-identical to the round-0 passing kernel
// (same fmaf chains/orders for every scalar), restructured for scheduling:
//  - 1024 threads/block (16 waves -> 4 waves/SIMD; was 1 wave/SIMD)
//  - odd strides (65) / 16B strides (68) in LDS -> no bank conflicts
//    (round-0's stride 66 caused the 1.5e8 conflict count)
//  - register-blocked projections: 8 rows/wave, j in octets, scalar weight
//    loads, y loaded once per octet (was re-read per output row)
//  - kq rows held in registers; softmax butterfly identical to round-0
//  - column 64 (x[64]=1 ragged column) via a 24-lane gathered side chain

__global__ __launch_bounds__(1024)
void literal_kernel(const float* __restrict__ in0,
                    const float* __restrict__ emb,
                    const float* __restrict__ wk11, const float* __restrict__ wq11,
                    const float* __restrict__ wv11,
                    const float* __restrict__ wk12, const float* __restrict__ wq12,
                    const float* __restrict__ wv12,
                    const float* __restrict__ l1,
                    const float* __restrict__ wk21, const float* __restrict__ wq21,
                    const float* __restrict__ wv21,
                    const float* __restrict__ wk22, const float* __restrict__ wq22,
                    const float* __restrict__ wv22,
                    const float* __restrict__ l2,
                    const float* __restrict__ L3, const float* __restrict__ L4,
                    float* __restrict__ out)
{
    __shared__ float xsh[66];
    __shared__ float ysh[128 * 65];                 // y[j][s]; later y2[h][s]
    __shared__ float ksh[128 * 65];                 // k[i][s]; att[s*128+i]; q2[i][t]
    __shared__ float qsh[128 * 65];                 // q[i][t]
    __shared__ __align__(16) float vsh[128 * 68];   // v[i][t] stride 68; v2 stride 65
    __shared__ __align__(16) float smsh[65 * 68];   // sm[s][t] stride 68
    __shared__ float kq64sh[65];
    __shared__ float k2col[128];
    __shared__ float attr[128];
    __shared__ float lshf[66];
    __shared__ float smr[66];
    __shared__ float y4sh[128];

    const int tid  = threadIdx.x;
    const int lane = tid & 63;
    const int wu   = __builtin_amdgcn_readfirstlane(tid >> 6);   // wave 0..15
    const long b   = blockIdx.x;

    if (tid < 64) xsh[tid] = in0[b * 64 + tid];
    if (tid == 64) xsh[64] = 1.0f;
    __syncthreads();

    // y[j][s] = emb[j][s] * x[s]   (stride 65, contiguous with emb)
    for (int idx = tid; idx < 8320; idx += 1024) {
        int s = idx % 65;
        ysh[idx] = emb[idx] * xsh[s];
    }
    __syncthreads();

    // pre1 accumulators: thread owns h = 4*(tid&31)..+3, s = (tid>>5) + 32*si
    const int h4 = (tid & 31) * 4;
    const int sb = tid >> 5;            // 0..31
    float4 acc1[3];
    acc1[0] = make_float4(0.f, 0.f, 0.f, 0.f);
    acc1[1] = make_float4(0.f, 0.f, 0.f, 0.f);
    acc1[2] = make_float4(0.f, 0.f, 0.f, 0.f);

    float* attsh = ksh;   // att[s*128+i] overwrites k after kq

    for (int a = 0; a < 2; ++a) {
        const float* wk = a ? wk12 : wk11;
        const float* wq = a ? wq12 : wq11;
        const float* wv = a ? wv12 : wv11;

        // ---- projections: wave wu computes rows i = wu*8 + r, lanes = col s ----
        {
            float aK[8], aQ[8], aV[8];
            #pragma unroll
            for (int r = 0; r < 8; ++r) { aK[r] = aQ[r] = aV[r] = 0.f; }
            float acc64 = 0.f;                       // col-64 side chain (24 lanes)
            const int i0 = wu * 8;
            const int ch = lane >> 3;                // 0:K 1:Q 2:V for lane<24
            const float* Wc = (ch == 0) ? wk : ((ch == 1) ? wq : wv);
            const float* wcrow = Wc + (i0 + (lane & 7)) * 128;

            for (int jb = 0; jb < 16; ++jb) {
                float yv[8], y64v[8];
                #pragma unroll
                for (int u = 0; u < 8; ++u) {
                    yv[u]   = ysh[(jb * 8 + u) * 65 + lane];
                    y64v[u] = ysh[(jb * 8 + u) * 65 + 64];
                }
                #pragma unroll
                for (int r = 0; r < 8; ++r) {
                    const float* wkr = wk + (i0 + r) * 128 + jb * 8;
                    const float* wqr = wq + (i0 + r) * 128 + jb * 8;
                    const float* wvr = wv + (i0 + r) * 128 + jb * 8;
                    #pragma unroll
                    for (int u = 0; u < 8; ++u) {
                        aK[r] = fmaf(wkr[u], yv[u], aK[r]);
                        aQ[r] = fmaf(wqr[u], yv[u], aQ[r]);
                        aV[r] = fmaf(wvr[u], yv[u], aV[r]);
                    }
                }
                if (lane < 24) {
                    float4 c0 = *(const float4*)&wcrow[jb * 8];
                    float4 c1 = *(const float4*)&wcrow[jb * 8 + 4];
                    acc64 = fmaf(c0.x, y64v[0], acc64);
                    acc64 = fmaf(c0.y, y64v[1], acc64);
                    acc64 = fmaf(c0.z, y64v[2], acc64);
                    acc64 = fmaf(c0.w, y64v[3], acc64);
                    acc64 = fmaf(c1.x, y64v[4], acc64);
                    acc64 = fmaf(c1.y, y64v[5], acc64);
                    acc64 = fmaf(c1.z, y64v[6], acc64);
                    acc64 = fmaf(c1.w, y64v[7], acc64);
                }
            }
            #pragma unroll
            for (int r = 0; r < 8; ++r) {
                int i = i0 + r;
                ksh[i * 65 + lane] = aK[r];
                qsh[i * 65 + lane] = aQ[r];
                vsh[i * 68 + lane] = aV[r];
            }
            if (lane < 8)       ksh[(i0 + lane) * 65 + 64]       = acc64;
            else if (lane < 16) qsh[(i0 + (lane & 7)) * 65 + 64] = acc64;
            else if (lane < 24) vsh[(i0 + (lane & 7)) * 68 + 64] = acc64;
        }
        __syncthreads();

        // ---- kq: wave wu owns rows s = 4*wu + rr (wave 15 also s=64) ----
        float kqa[5];
        kqa[0] = kqa[1] = kqa[2] = kqa[3] = kqa[4] = 0.f;
        if (tid < 65) {                       // column t = 64
            float acc = 0.f;
            for (int i = 0; i < 128; ++i)
                acc = fmaf(ksh[i * 65 + tid], qsh[i * 65 + 64], acc);
            kq64sh[tid] = acc;
        }
        {
            const int sbase = 4 * wu;
            for (int i = 0; i < 128; ++i) {
                float qv = qsh[i * 65 + lane];
                const float* kro = &ksh[i * 65];
                kqa[0] = fmaf(kro[sbase + 0], qv, kqa[0]);
                kqa[1] = fmaf(kro[sbase + 1], qv, kqa[1]);
                kqa[2] = fmaf(kro[sbase + 2], qv, kqa[2]);
                kqa[3] = fmaf(kro[sbase + 3], qv, kqa[3]);
                if (wu == 15) kqa[4] = fmaf(kro[64], qv, kqa[4]);
            }
        }
        __syncthreads();

        // ---- softmax over t, rows in registers (round-0 butterfly DAG) ----
        #pragma unroll
        for (int rr = 0; rr < 5; ++rr) {
            if (rr < 4 || wu == 15) {
                int s = (rr == 4) ? 64 : 4 * wu + rr;
                float lg   = kqa[rr];
                float l64v = (lane == 0) ? kq64sh[s] : -3.0e38f;
                float mm = fmaxf(lg, l64v);
                #pragma unroll
                for (int off = 32; off >= 1; off >>= 1) mm = fmaxf(mm, __shfl_xor(mm, off));
                float e   = expf(lg - mm);
                float e64 = (lane == 0) ? expf(l64v - mm) : 0.f;
                float zs = e + e64;
                #pragma unroll
                for (int off = 32; off >= 1; off >>= 1) zs += __shfl_xor(zs, off);
                float inv = 1.0f / zs;
                smsh[s * 68 + lane] = e * inv;
                if (lane == 0) smsh[s * 68 + 64] = e64 * inv;
            }
        }
        __syncthreads();

        // ---- att[s][i] = sum_t sm[s][t]*v[i][t]; float4 along t ----
        {
            const int iA = tid & 127;
            const int sg = tid >> 7;           // 0..7, uniform per wave
            float aa[9];
            #pragma unroll
            for (int m = 0; m < 9; ++m) aa[m] = 0.f;
            for (int k = 0; k < 16; ++k) {
                float4 vq = *(const float4*)&vsh[iA * 68 + 4 * k];
                #pragma unroll
                for (int m = 0; m < 9; ++m) {
                    if (m < 8 || sg == 0) {
                        int s = sg + 8 * m;
                        float4 sq = *(const float4*)&smsh[s * 68 + 4 * k];
                        aa[m] = fmaf(sq.x, vq.x, aa[m]);
                        aa[m] = fmaf(sq.y, vq.y, aa[m]);
                        aa[m] = fmaf(sq.z, vq.z, aa[m]);
                        aa[m] = fmaf(sq.w, vq.w, aa[m]);
                    }
                }
            }
            float v64 = vsh[iA * 68 + 64];
            #pragma unroll
            for (int m = 0; m < 9; ++m) {
                if (m < 8 || sg == 0) {
                    int s = sg + 8 * m;
                    aa[m] = fmaf(smsh[s * 68 + 64], v64, aa[m]);
                    attsh[s * 128 + iA] = aa[m];
                }
            }
        }
        __syncthreads();

        // ---- pre1[s][h] += sum_i att[s][i]*l1a[i][h] ----
        {
            const float* l1a = l1 + a * (128 * 128);
            for (int i = 0; i < 128; ++i) {
                float4 lv = *(const float4*)&l1a[i * 128 + h4];
                #pragma unroll
                for (int si = 0; si < 3; ++si) {
                    if (si < 2 || sb == 0) {
                        int s = sb + 32 * si;
                        float av = attsh[s * 128 + i];
                        acc1[si].x = fmaf(av, lv.x, acc1[si].x);
                        acc1[si].y = fmaf(av, lv.y, acc1[si].y);
                        acc1[si].z = fmaf(av, lv.z, acc1[si].z);
                        acc1[si].w = fmaf(av, lv.w, acc1[si].w);
                    }
                }
            }
        }
        __syncthreads();
    }

    // ---- y2[h][s] = tanh(pre1[s][h])  (into ysh region) ----
    float* y2sh = ysh;
    #pragma unroll
    for (int si = 0; si < 3; ++si) {
        if (si < 2 || sb == 0) {
            int s = sb + 32 * si;
            y2sh[(h4 + 0) * 65 + s] = tanhf(acc1[si].x);
            y2sh[(h4 + 1) * 65 + s] = tanhf(acc1[si].y);
            y2sh[(h4 + 2) * 65 + s] = tanhf(acc1[si].z);
            y2sh[(h4 + 3) * 65 + s] = tanhf(acc1[si].w);
        }
    }
    __syncthreads();

    // ---- stage 2 (literal; only row s=64 used downstream) ----
    float* q2sh = ksh;
    float* v2sh = vsh;          // stride 65 now
    float pre2 = 0.f;           // valid for tid < 128

    for (int a2 = 0; a2 < 2; ++a2) {
        const float* wk2 = a2 ? wk22 : wk21;
        const float* wq2 = a2 ? wq22 : wq21;
        const float* wv2 = a2 ? wv22 : wv21;

        {
            float aQ[8], aV[8];
            #pragma unroll
            for (int r = 0; r < 8; ++r) { aQ[r] = aV[r] = 0.f; }
            float acc64 = 0.f;               // 0..7: q2 col64, 8..15: v2 col64, 16..23: k2col
            const int i0 = wu * 8;
            const int ch = lane >> 3;
            const float* Wc = (ch == 0) ? wq2 : ((ch == 1) ? wv2 : wk2);
            const float* wcrow = Wc + (i0 + (lane & 7)) * 128;

            for (int jb = 0; jb < 16; ++jb) {
                float yv[8], y64v[8];
                #pragma unroll
                for (int u = 0; u < 8; ++u) {
                    yv[u]   = y2sh[(jb * 8 + u) * 65 + lane];
                    y64v[u] = y2sh[(jb * 8 + u) * 65 + 64];
                }
                #pragma unroll
                for (int r = 0; r < 8; ++r) {
                    const float* wqr = wq2 + (i0 + r) * 128 + jb * 8;
                    const float* wvr = wv2 + (i0 + r) * 128 + jb * 8;
                    #pragma unroll
                    for (int u = 0; u < 8; ++u) {
                        aQ[r] = fmaf(wqr[u], yv[u], aQ[r]);
                        aV[r] = fmaf(wvr[u], yv[u], aV[r]);
                    }
                }
                if (lane < 24) {
                    float4 c0 = *(const float4*)&wcrow[jb * 8];
                    float4 c1 = *(const float4*)&wcrow[jb * 8 + 4];
                    acc64 = fmaf(c0.x, y64v[0], acc64);
                    acc64 = fmaf(c0.y, y64v[1], acc64);
                    acc64 = fmaf(c0.z, y64v[2], acc64);
                    acc64 = fmaf(c0.w, y64v[3], acc64);
                    acc64 = fmaf(c1.x, y64v[4], acc64);
                    acc64 = fmaf(c1.y, y64v[5], acc64);
                    acc64 = fmaf(c1.z, y64v[6], acc64);
                    acc64 = fmaf(c1.w, y64v[7], acc64);
                }
            }
            #pragma unroll
            for (int r = 0; r < 8; ++r) {
                int i = i0 + r;
                q2sh[i * 65 + lane] = aQ[r];
                v2sh[i * 65 + lane] = aV[r];
            }
            if (lane < 8)       q2sh[(i0 + lane) * 65 + 64]       = acc64;
            else if (lane < 16) v2sh[(i0 + (lane & 7)) * 65 + 64] = acc64;
            else if (lane < 24) k2col[i0 + (lane & 7)]            = acc64;
        }
        __syncthreads();

        // kq2[64][t] = sum_i k2col[i]*q2[i][t]
        if (tid < 65) {
            float acc = 0.f;
            for (int i = 0; i < 128; ++i)
                acc = fmaf(k2col[i], q2sh[i * 65 + tid], acc);
            lshf[tid] = acc;
        }
        __syncthreads();

        if (tid < 64) {
            float lg   = lshf[lane];
            float l64v = (lane == 0) ? lshf[64] : -3.0e38f;
            float mm = fmaxf(lg, l64v);
            #pragma unroll
            for (int off = 32; off >= 1; off >>= 1) mm = fmaxf(mm, __shfl_xor(mm, off));
            float e   = expf(lg - mm);
            float e64 = (lane == 0) ? expf(l64v - mm) : 0.f;
            float zs = e + e64;
            #pragma unroll
            for (int off = 32; off >= 1; off >>= 1) zs += __shfl_xor(zs, off);
            float inv = 1.0f / zs;
            smr[lane] = e * inv;
            if (lane == 0) smr[64] = e64 * inv;
        }
        __syncthreads();

        // att2[64][i] = sum_t sm2[t]*v2[i][t]
        if (tid < 128) {
            float acc = 0.f;
            for (int t = 0; t < 65; ++t)
                acc = fmaf(smr[t], v2sh[tid * 65 + t], acc);
            attr[tid] = acc;
        }
        __syncthreads();

        // pre2[h] += sum_i att2[i]*l2a[i][h]
        if (tid < 128) {
            const float* l2a = l2 + a2 * (128 * 128);
            float acc = pre2;
            for (int i = 0; i < 128; ++i)
                acc = fmaf(attr[i], l2a[i * 128 + tid], acc);
            pre2 = acc;
        }
        __syncthreads();
    }

    if (tid < 128) y4sh[tid] = tanhf(pre2);
    __syncthreads();

    if (tid < 64) {
        float t3 = 0.f;
        for (int h = 0; h < 128; ++h)
            t3 = fmaf(y4sh[h], L3[h * 64 + tid], t3);
        float y5 = tanhf(t3);
        float sc = y5 * L4[tid];
        #pragma unroll
        for (int off = 32; off >= 1; off >>= 1) sc += __shfl_xor(sc, off);
        if (tid == 0) out[b] = sc;
    }
}

extern "C" void kernel_launch(void* const* d_in, const int* in_sizes, int n_in,
                              void* d_out, int out_size, void* d_ws, size_t ws_size,
                              hipStream_t stream) {
    const float* in0  = (const float*)d_in[0];
    const float* emb  = (const float*)d_in[1];
    const float* wk11 = (const float*)d_in[2];
    const float* wq11 = (const float*)d_in[3];
    const float* wv11 = (const float*)d_in[4];
    const float* wk12 = (const float*)d_in[5];
    const float* wq12 = (const float*)d_in[6];
    const float* wv12 = (const float*)d_in[7];
    const float* l1   = (const float*)d_in[8];
    const float* wk21 = (const float*)d_in[9];
    const float* wq21 = (const float*)d_in[10];
    const float* wv21 = (const float*)d_in[11];
    const float* wk22 = (const float*)d_in[12];
    const float* wq22 = (const float*)d_in[13];
    const float* wv22 = (const float*)d_in[14];
    const float* l2   = (const float*)d_in[15];
    const float* l3   = (const float*)d_in[16];
    const float* l4   = (const float*)d_in[17];
    float* out = (float*)d_out;

    int B = in_sizes[0] / 64;   // 8192

    literal_kernel<<<B, 1024, 0, stream>>>(in0, emb,
                                           wk11, wq11, wv11, wk12, wq12, wv12, l1,
                                           wk21, wq21, wv21, wk22, wq22, wv22, l2,
                                           l3, l4, out);
}